// Round 9
// baseline (640.213 us; speedup 1.0000x reference)
//
#include <hip/hip_runtime.h>

using f32x4  = __attribute__((ext_vector_type(4))) float;
using u16x8  = __attribute__((ext_vector_type(8))) unsigned short;
using u16x4  = __attribute__((ext_vector_type(4))) unsigned short;
using bf16x8 = __attribute__((ext_vector_type(8))) __bf16;

__device__ __forceinline__ unsigned short f2bf(float f){
  return __builtin_bit_cast(unsigned short, (__bf16)f);   // compiler RNE cvt
}
__device__ __forceinline__ float bf2f(unsigned short h){
  return __builtin_bit_cast(float, ((unsigned int)h) << 16);
}
__device__ __forceinline__ f32x4 mfma_bf16(u16x8 a, u16x8 b, f32x4 c){
  return __builtin_amdgcn_mfma_f32_16x16x32_bf16(
      __builtin_bit_cast(bf16x8, a), __builtin_bit_cast(bf16x8, b), c, 0, 0, 0);
}
__device__ __forceinline__ float fast_sigmoid(float x){
  return __builtin_amdgcn_rcpf(1.0f + __builtin_amdgcn_exp2f(-1.44269504f * x));
}

constexpr int CHW = 256 * 64;   // 16384

// Raw barrier: LDS ops drained, global prefetch loads stay in flight
#define BAR_LDS() do {                                        \
    asm volatile("s_waitcnt lgkmcnt(0)" ::: "memory");        \
    __builtin_amdgcn_s_barrier();                             \
    asm volatile("" ::: "memory");                            \
  } while (0)

// 8-pixel tile LDS layout (bf16, 256 c x 8 p): el(c,p) = ((c>>3)*8 + p)*8 + (c&7)
// B-fragment (kc, lane): b128 at kc*256 + (lane>>4)*64 + (lane&7)*8   [cols 8-15 broadcast]
// staging thread t (rows ss*8..+7, px sp): b128 at (ss*8+sp)*8
// epilogue rows ro..ro+3 (ro = (wv*4+mi)*16 + g*4), col mc: b64 at
//   el0 + mi*128,  el0 = ((wv*8 + (g>>1))*8 + mc)*8 + (g&1)*4

__global__ __launch_bounds__(256, 2)
void kalman_kernel(const float* __restrict__ z,  const float* __restrict__ Wg,
                   const float* __restrict__ bg, const float* __restrict__ Wp,
                   const float* __restrict__ bp, float* __restrict__ out)
{
  __shared__ unsigned short zbuf[3][2048];   // z triple buffer (2-step prefetch)
  __shared__ unsigned short sbuf[2][2048];   // state ping-pong (bf16)

  // Grid 512 = (b 64) x (octant o 8). Same-b siblings share an XCD (lx&7 = b&7),
  // so their half-cache-line z reads are served by the shared L2.
  const int lx = (int)blockIdx.x;
  const int b  = (lx & 7) + 8 * (lx >> 6);
  const int o  = (lx >> 3) & 7;

  const int t    = (int)threadIdx.x;
  const int lane = t & 63;
  const int wv   = t >> 6;            // 0..3, owns M-tiles wv*4..wv*4+3
  const int m    = lane & 15;
  const int mc   = m & 7;             // real pixel column (8-15 mirror 0-7)
  const int g    = lane >> 4;

  const float* zg = z + (size_t)b * 64 * CHW + o * 8;

  // ---- both weight matrices for this wave's 4 M-tiles (128 VGPRs) ----
  u16x8 wfP[4][8], wfG[4][8];
  f32x4 bP[4], bG[4];
  #pragma unroll
  for (int mi = 0; mi < 4; ++mi){
    const int mt = wv * 4 + mi;
    const float* srcP = Wp + (size_t)(mt * 16 + m) * 256 + g * 8;
    const float* srcG = Wg + (size_t)(mt * 16 + m) * 256 + g * 8;
    #pragma unroll
    for (int kc = 0; kc < 8; ++kc){
      #pragma unroll
      for (int j = 0; j < 8; ++j){
        wfP[mi][kc][j] = f2bf(srcP[kc * 32 + j]);
        wfG[mi][kc][j] = f2bf(srcG[kc * 32 + j]);
      }
    }
    bP[mi] = *(const f32x4*)(bp + mt * 16 + g * 4);
    bG[mi] = *(const f32x4*)(bg + mt * 16 + g * 4);
  }

  // ---- staging ids: thread t stages rows ss*8..+7 at pixel sp ----
  const int sp = t & 7;
  const int ss = t >> 3;              // 0..31
  const float* st_src = zg + ss * 8 * 64 + sp;
  const int st_dst = (ss * 8 + sp) * 8;

  // prologue: s0 -> sbuf[0], z1 -> zbuf[1], z2 -> zbuf[2]; z3 in flight
  {
    u16x8 u0, u1, u2;
    #pragma unroll
    for (int j = 0; j < 8; ++j){
      u0[j] = f2bf(st_src[j * 64]);
      u1[j] = f2bf(st_src[CHW + j * 64]);
      u2[j] = f2bf(st_src[2 * CHW + j * 64]);
    }
    *(u16x8*)(&sbuf[0][st_dst]) = u0;
    *(u16x8*)(&zbuf[1][st_dst]) = u1;
    *(u16x8*)(&zbuf[2][st_dst]) = u2;
  }
  float pf[8];
  const float* pfp = st_src + 3 * (size_t)CHW;
  #pragma unroll
  for (int j = 0; j < 8; ++j) pf[j] = pfp[j * 64];
  pfp += CHW;                          // next issue: z4
  __syncthreads();

  const int boff = g * 64 + mc * 8;
  const int el0  = ((wv * 8 + (g >> 1)) * 8 + mc) * 8 + (g & 1) * 4;

  // ---- k_1 from z_1 (lane-local rows; lives in registers) ----
  f32x4 kcur[4];
  {
    f32x4 gl[4] = {bG[0], bG[1], bG[2], bG[3]};
    #pragma unroll
    for (int kc = 0; kc < 8; ++kc){
      u16x8 zf = *(const u16x8*)(&zbuf[1][kc * 256 + boff]);
      #pragma unroll
      for (int mi = 0; mi < 4; ++mi)
        gl[mi] = mfma_bf16(wfG[mi][kc], zf, gl[mi]);
    }
    #pragma unroll
    for (int mi = 0; mi < 4; ++mi)
      #pragma unroll
      for (int r = 0; r < 4; ++r) kcur[mi][r] = fast_sigmoid(gl[mi][r]);
  }

  for (int l = 1; l < 63; ++l){
    // commit z_{l+2} (loaded last step), issue z_{l+3}
    if (l <= 61){
      u16x8 u;
      #pragma unroll
      for (int j = 0; j < 8; ++j) u[j] = f2bf(pf[j]);
      *(u16x8*)(&zbuf[(l + 2) % 3][st_dst]) = u;
    }
    if (l <= 60){
      #pragma unroll
      for (int j = 0; j < 8; ++j) pf[j] = pfp[j * 64];
      pfp += CHW;
    }

    const unsigned short* sb  = sbuf[(l - 1) & 1];
    const unsigned short* zbl = zbuf[l % 3];        // z_l   (blend)
    const unsigned short* zbn = zbuf[(l + 1) % 3];  // z_{l+1} (gain for next step)
    unsigned short* sbw = sbuf[l & 1];

    u16x4 zi4[4];
    #pragma unroll
    for (int mi = 0; mi < 4; ++mi) zi4[mi] = *(const u16x4*)(zbl + el0 + mi * 128);

    // predict (state) + gain (z_{l+1}) matvecs, interleaved; 8 indep chains depth 8
    f32x4 zp[4] = {bP[0], bP[1], bP[2], bP[3]};
    f32x4 gl[4] = {bG[0], bG[1], bG[2], bG[3]};
    #pragma unroll
    for (int kc = 0; kc < 8; ++kc){
      u16x8 sfv = *(const u16x8*)(sb  + kc * 256 + boff);
      u16x8 zfv = *(const u16x8*)(zbn + kc * 256 + boff);
      #pragma unroll
      for (int mi = 0; mi < 4; ++mi) zp[mi] = mfma_bf16(wfP[mi][kc], sfv, zp[mi]);
      #pragma unroll
      for (int mi = 0; mi < 4; ++mi) gl[mi] = mfma_bf16(wfG[mi][kc], zfv, gl[mi]);
    }

    // blend with k_l (regs), write s_l (cols 0-7 only)
    #pragma unroll
    for (int mi = 0; mi < 4; ++mi){
      u16x4 sh;
      #pragma unroll
      for (int r = 0; r < 4; ++r){
        float zpr = zp[mi][r];
        float zh  = zpr + kcur[mi][r] * (bf2f(zi4[mi][r]) - zpr);
        sh[r] = f2bf(zh);
      }
      if (m < 8) *(u16x4*)(sbw + el0 + mi * 128) = sh;
    }
    // k_{l+1}
    #pragma unroll
    for (int mi = 0; mi < 4; ++mi)
      #pragma unroll
      for (int r = 0; r < 4; ++r) kcur[mi][r] = fast_sigmoid(gl[mi][r]);

    BAR_LDS();
  }

  // ---- peeled final step l = 63: predict s_62, blend k_63, write out (f32) ----
  {
    const unsigned short* sb  = sbuf[0];     // s_62  ((63-1)&1)
    const unsigned short* zbl = zbuf[0];     // z_63  (63%3)

    u16x4 zi4[4];
    #pragma unroll
    for (int mi = 0; mi < 4; ++mi) zi4[mi] = *(const u16x4*)(zbl + el0 + mi * 128);

    f32x4 zp[4] = {bP[0], bP[1], bP[2], bP[3]};
    #pragma unroll
    for (int kc = 0; kc < 8; ++kc){
      u16x8 sfv = *(const u16x8*)(sb + kc * 256 + boff);
      #pragma unroll
      for (int mi = 0; mi < 4; ++mi) zp[mi] = mfma_bf16(wfP[mi][kc], sfv, zp[mi]);
    }

    if (m < 8){
      #pragma unroll
      for (int mi = 0; mi < 4; ++mi){
        const int ro = (wv * 4 + mi) * 16 + g * 4;
        float* op = out + ((size_t)b * 256 + ro) * 64 + o * 8 + mc;
        #pragma unroll
        for (int r = 0; r < 4; ++r){
          float zpr = zp[mi][r];
          op[r * 64] = zpr + kcur[mi][r] * (bf2f(zi4[mi][r]) - zpr);
        }
      }
    }
  }
}

extern "C" void kernel_launch(void* const* d_in, const int* in_sizes, int n_in,
                              void* d_out, int out_size, void* d_ws, size_t ws_size,
                              hipStream_t stream)
{
  const float* z  = (const float*)d_in[0];
  const float* Wg = (const float*)d_in[1];
  const float* bg = (const float*)d_in[2];
  const float* Wp = (const float*)d_in[3];
  const float* bp = (const float*)d_in[4];
  float* out = (float*)d_out;
  hipLaunchKernelGGL(kalman_kernel, dim3(512), dim3(256), 0, stream,
                     z, Wg, bg, Wp, bp, out);
}

// Round 10
// 137.710 us; speedup vs baseline: 4.6490x; 4.6490x over previous
//
#include <hip/hip_runtime.h>

using f32x4  = __attribute__((ext_vector_type(4))) float;
using u16x8  = __attribute__((ext_vector_type(8))) unsigned short;
using u16x4  = __attribute__((ext_vector_type(4))) unsigned short;
using bf16x8 = __attribute__((ext_vector_type(8))) __bf16;

__device__ __forceinline__ unsigned short f2bf(float f){
  return __builtin_bit_cast(unsigned short, (__bf16)f);      // RNE (R9-proven)
}
__device__ __forceinline__ float bf2f(unsigned short h){
  return __builtin_bit_cast(float, ((unsigned int)h) << 16);
}
__device__ __forceinline__ unsigned short f2h(float f){
  return __builtin_bit_cast(unsigned short, (_Float16)f);
}
__device__ __forceinline__ float h2f(unsigned short h){
  return (float)__builtin_bit_cast(_Float16, h);
}
__device__ __forceinline__ f32x4 mfma_bf16(u16x8 a, u16x8 b, f32x4 c){
  return __builtin_amdgcn_mfma_f32_16x16x32_bf16(
      __builtin_bit_cast(bf16x8, a), __builtin_bit_cast(bf16x8, b), c, 0, 0, 0);
}
__device__ __forceinline__ float fast_sigmoid(float x){
  return __builtin_amdgcn_rcpf(1.0f + __builtin_amdgcn_exp2f(-1.44269504f * x));
}

constexpr int C_  = 256;
constexpr int L_  = 64;
constexpr int CHW = C_ * 64;   // 16384

// Raw barrier: LDS ops drained, global prefetch loads stay in flight
#define BAR_LDS() do {                                        \
    asm volatile("s_waitcnt lgkmcnt(0)" ::: "memory");        \
    __builtin_amdgcn_s_barrier();                             \
    asm volatile("" ::: "memory");                            \
  } while (0)

// LDS operand layout (bf16/fp16, 256 c x 16 p): el(c,p) = ((c>>3)*16 + p)*8 + (c&7)
// B-fragment (kc, lane): b128 at kc*512 + (lane>>4)*128 + (lane&15)*8
// staging: b128 at (octet*16 + pixel)*8 ; epilogue rows ro..ro+3: b64 at
// ((ro>>3)*16 + m)*8 + (ro&7)
//
// Phase-skewed schedule (per step l, lgkm-barrier-synced):
//   P (waves 0-3): ds_read s,zi,k -> setprio(1) 32 MFMA -> blend -> write s_l
//   G (waves 4-7): ds_read z_{l+1} -> issue gload z_{l+3} -> 32 MFMA ->
//                  sigmoid -> write k_{l+1} -> cvt+commit z_{l+2}
// G's VALU tail overlaps P's barrier wait / next-step head; P's MFMA claims
// the matrix pipe first via setprio.

__global__ __launch_bounds__(512, 2)
void kalman_kernel(const float* __restrict__ z,  const float* __restrict__ Wg,
                   const float* __restrict__ bg, const float* __restrict__ Wp,
                   const float* __restrict__ bp, float* __restrict__ out)
{
  __shared__ unsigned short zbuf[4][4096];   // z ring (slot j&3)
  __shared__ unsigned short sbuf[2][4096];   // state ping-pong (bf16)
  __shared__ unsigned short kbuf[2][4096];   // gain k ping-pong (fp16)

  // XCD swizzle: q-siblings of one b share an XCD's L2 (z lines span q pairs)
  const int lx  = (int)blockIdx.x;
  const int b   = (lx & 7) + 8 * ((lx >> 3) >> 2);
  const int q   = (lx >> 3) & 3;

  const int t    = (int)threadIdx.x;
  const int lane = t & 63;
  const int wv   = t >> 6;
  const int role = wv >> 2;           // 0 = P (pure recurrence), 1 = G (gain + staging)
  const int rw   = wv & 3;            // owns M-tiles rw*4 .. rw*4+3
  const int m    = lane & 15;
  const int g    = lane >> 4;

  const float* zg = z + (size_t)b * L_ * CHW + q * 16;

  // ---- per-role weights: 4 M-tiles x 8 K-chunks in regs ----
  const float* Wsel = (role == 0) ? Wp : Wg;
  const float* bsrc = (role == 0) ? bp : bg;
  u16x8 wf[4][8];
  f32x4 bsel[4];
  #pragma unroll
  for (int mi = 0; mi < 4; ++mi){
    const int mt = rw * 4 + mi;
    const float* src = Wsel + (size_t)(mt * 16 + m) * 256 + g * 8;
    #pragma unroll
    for (int kc = 0; kc < 8; ++kc){
      #pragma unroll
      for (int j = 0; j < 8; ++j) wf[mi][kc][j] = f2bf(src[kc * 32 + j]);
    }
    bsel[mi] = *(const f32x4*)(bsrc + mt * 16 + g * 4);
  }

  // ---- prologue: ALL threads stage s_0, z_1, z_2 (8 els each) ----
  {
    const int sp = t & 15;
    const int ss = t >> 4;
    const float* s0 = zg + ss * 8 * 64 + sp;
    const int dst = (ss * 16 + sp) * 8;
    u16x8 u0, u1, u2;
    #pragma unroll
    for (int j = 0; j < 8; ++j){
      u0[j] = f2bf(s0[j * 64]);
      u1[j] = f2bf(s0[CHW + j * 64]);
      u2[j] = f2bf(s0[2 * CHW + j * 64]);
    }
    *(u16x8*)(&sbuf[0][dst]) = u0;
    *(u16x8*)(&zbuf[1][dst]) = u1;
    *(u16x8*)(&zbuf[2][dst]) = u2;
  }

  // ---- G staging ids (16 els/thread/step) + issue z_3 ----
  const int sp2 = lane & 15;
  const int so2 = rw * 4 + (lane >> 4);          // octets so2 and so2+16
  const float* zsrc0 = zg + so2 * 8 * 64 + sp2;
  const float* zsrc1 = zg + (so2 + 16) * 8 * 64 + sp2;
  const float* pf0 = zsrc0 + 4 * (size_t)CHW;    // next ISSUE: z_4
  const float* pf1 = zsrc1 + 4 * (size_t)CHW;
  float pfA[8], pfB[8];
  if (role == 1){
    #pragma unroll
    for (int i = 0; i < 8; ++i){
      pfA[i] = zsrc0[3 * CHW + i * 64];           // z_3 in flight
      pfB[i] = zsrc1[3 * CHW + i * 64];
    }
  }
  __syncthreads();

  const int boff = g * 128 + m * 8;

  // ---- k_1 from z_1 (G only) ----
  if (role == 1){
    u16x8 zf[8];
    #pragma unroll
    for (int kc = 0; kc < 8; ++kc) zf[kc] = *(const u16x8*)(&zbuf[1][kc * 512 + boff]);
    f32x4 gl[4] = {bsel[0], bsel[1], bsel[2], bsel[3]};
    #pragma unroll
    for (int kc = 0; kc < 8; ++kc)
      #pragma unroll
      for (int mi = 0; mi < 4; ++mi)
        gl[mi] = mfma_bf16(wf[mi][kc], zf[kc], gl[mi]);
    #pragma unroll
    for (int mi = 0; mi < 4; ++mi){
      const int ro = (rw * 4 + mi) * 16 + g * 4;
      const int el = ((ro >> 3) * 16 + m) * 8 + (ro & 7);
      u16x4 kk;
      #pragma unroll
      for (int r = 0; r < 4; ++r) kk[r] = f2h(fast_sigmoid(gl[mi][r]));
      *(u16x4*)(&kbuf[1][el]) = kk;
    }
  }
  __syncthreads();

  for (int l = 1; l < 63; ++l){
    if (role == 0){
      // ================= P: pure recurrence =================
      const unsigned short* sb  = sbuf[(l - 1) & 1];
      const unsigned short* zbl = zbuf[l & 3];
      const unsigned short* kb  = kbuf[l & 1];
      unsigned short* sbw = sbuf[l & 1];

      u16x8 sf[8];
      #pragma unroll
      for (int kc = 0; kc < 8; ++kc) sf[kc] = *(const u16x8*)(sb + kc * 512 + boff);
      u16x4 zi4[4], k4[4];
      #pragma unroll
      for (int mi = 0; mi < 4; ++mi){
        const int ro = (rw * 4 + mi) * 16 + g * 4;
        const int el = ((ro >> 3) * 16 + m) * 8 + (ro & 7);
        zi4[mi] = *(const u16x4*)(zbl + el);
        k4[mi]  = *(const u16x4*)(kb + el);
      }

      f32x4 zpA[4] = {bsel[0], bsel[1], bsel[2], bsel[3]};
      f32x4 zpB[4] = {{0,0,0,0},{0,0,0,0},{0,0,0,0},{0,0,0,0}};
      __builtin_amdgcn_s_setprio(1);
      #pragma unroll
      for (int kc = 0; kc < 4; ++kc)
        #pragma unroll
        for (int mi = 0; mi < 4; ++mi){
          zpA[mi] = mfma_bf16(wf[mi][kc],     sf[kc],     zpA[mi]);
          zpB[mi] = mfma_bf16(wf[mi][kc + 4], sf[kc + 4], zpB[mi]);
        }
      __builtin_amdgcn_s_setprio(0);

      #pragma unroll
      for (int mi = 0; mi < 4; ++mi){
        const int ro = (rw * 4 + mi) * 16 + g * 4;
        const int el = ((ro >> 3) * 16 + m) * 8 + (ro & 7);
        u16x4 sh;
        #pragma unroll
        for (int r = 0; r < 4; ++r){
          float zpr = zpA[mi][r] + zpB[mi][r];
          float zh  = zpr + h2f(k4[mi][r]) * (bf2f(zi4[mi][r]) - zpr);
          sh[r] = f2bf(zh);
        }
        *(u16x4*)(sbw + el) = sh;
      }
    } else {
      // ================= G: gain (for l+1) + all staging =================
      const unsigned short* zb = zbuf[(l + 1) & 3];
      unsigned short* kw = kbuf[(l + 1) & 1];

      u16x8 zf[8];
      #pragma unroll
      for (int kc = 0; kc < 8; ++kc) zf[kc] = *(const u16x8*)(zb + kc * 512 + boff);

      // issue z_{l+3}: consumed at step l+1's commit -> full-step latency cover
      float nA[8], nB[8];
      if (l <= 60){
        #pragma unroll
        for (int i = 0; i < 8; ++i){ nA[i] = pf0[i * 64]; nB[i] = pf1[i * 64]; }
        pf0 += CHW; pf1 += CHW;
      }

      f32x4 gl[4] = {bsel[0], bsel[1], bsel[2], bsel[3]};
      #pragma unroll
      for (int kc = 0; kc < 8; ++kc)
        #pragma unroll
        for (int mi = 0; mi < 4; ++mi)
          gl[mi] = mfma_bf16(wf[mi][kc], zf[kc], gl[mi]);

      #pragma unroll
      for (int mi = 0; mi < 4; ++mi){
        const int ro = (rw * 4 + mi) * 16 + g * 4;
        const int el = ((ro >> 3) * 16 + m) * 8 + (ro & 7);
        u16x4 kk;
        #pragma unroll
        for (int r = 0; r < 4; ++r) kk[r] = f2h(fast_sigmoid(gl[mi][r]));
        *(u16x4*)(kw + el) = kk;
      }

      // commit z_{l+2} (loaded at step l-1)
      if (l <= 61){
        u16x8 u0, u1;
        #pragma unroll
        for (int i = 0; i < 8; ++i){ u0[i] = f2bf(pfA[i]); u1[i] = f2bf(pfB[i]); }
        *(u16x8*)(&zbuf[(l + 2) & 3][(so2 * 16 + sp2) * 8]) = u0;
        *(u16x8*)(&zbuf[(l + 2) & 3][((so2 + 16) * 16 + sp2) * 8]) = u1;
      }
      // rotate prefetch regs
      if (l <= 60){
        #pragma unroll
        for (int i = 0; i < 8; ++i){ pfA[i] = nA[i]; pfB[i] = nB[i]; }
      }
    }

    BAR_LDS();
  }

  // ---- peeled final step l = 63 (P only): out (f32) from regs ----
  if (role == 0){
    const unsigned short* sb  = sbuf[0];          // s_62
    const unsigned short* zbl = zbuf[3];          // z_63 (committed at l=61)
    const unsigned short* kb  = kbuf[1];          // k_63 (written at l=62)

    u16x8 sf[8];
    #pragma unroll
    for (int kc = 0; kc < 8; ++kc) sf[kc] = *(const u16x8*)(sb + kc * 512 + boff);
    u16x4 zi4[4], k4[4];
    #pragma unroll
    for (int mi = 0; mi < 4; ++mi){
      const int ro = (rw * 4 + mi) * 16 + g * 4;
      const int el = ((ro >> 3) * 16 + m) * 8 + (ro & 7);
      zi4[mi] = *(const u16x4*)(zbl + el);
      k4[mi]  = *(const u16x4*)(kb + el);
    }

    f32x4 zpA[4] = {bsel[0], bsel[1], bsel[2], bsel[3]};
    f32x4 zpB[4] = {{0,0,0,0},{0,0,0,0},{0,0,0,0},{0,0,0,0}};
    #pragma unroll
    for (int kc = 0; kc < 4; ++kc)
      #pragma unroll
      for (int mi = 0; mi < 4; ++mi){
        zpA[mi] = mfma_bf16(wf[mi][kc],     sf[kc],     zpA[mi]);
        zpB[mi] = mfma_bf16(wf[mi][kc + 4], sf[kc + 4], zpB[mi]);
      }

    #pragma unroll
    for (int mi = 0; mi < 4; ++mi){
      const int ro = (rw * 4 + mi) * 16 + g * 4;
      float* o = out + ((size_t)b * 256 + ro) * 64 + q * 16 + m;
      #pragma unroll
      for (int r = 0; r < 4; ++r){
        float zpr = zpA[mi][r] + zpB[mi][r];
        o[r * 64] = zpr + h2f(k4[mi][r]) * (bf2f(zi4[mi][r]) - zpr);
      }
    }
  }
}

extern "C" void kernel_launch(void* const* d_in, const int* in_sizes, int n_in,
                              void* d_out, int out_size, void* d_ws, size_t ws_size,
                              hipStream_t stream)
{
  const float* z  = (const float*)d_in[0];
  const float* Wg = (const float*)d_in[1];
  const float* bg = (const float*)d_in[2];
  const float* Wp = (const float*)d_in[3];
  const float* bp = (const float*)d_in[4];
  float* out = (float*)d_out;
  hipLaunchKernelGGL(kalman_kernel, dim3(256), dim3(512), 0, stream,
                     z, Wg, bg, Wp, bp, out);
}

// Round 11
// 90.329 us; speedup vs baseline: 7.0876x; 1.5245x over previous
//
#include <hip/hip_runtime.h>

using f32x4  = __attribute__((ext_vector_type(4))) float;
using u16x8  = __attribute__((ext_vector_type(8))) unsigned short;
using u16x4  = __attribute__((ext_vector_type(4))) unsigned short;
using bf16x8 = __attribute__((ext_vector_type(8))) __bf16;

__device__ __forceinline__ unsigned short f2bf(float f){
  unsigned int u = __builtin_bit_cast(unsigned int, f);
  u += 0x7fffu + ((u >> 16) & 1u);          // RNE to bf16
  return (unsigned short)(u >> 16);
}
__device__ __forceinline__ float bf2f(unsigned short h){
  return __builtin_bit_cast(float, ((unsigned int)h) << 16);
}
__device__ __forceinline__ unsigned short f2h(float f){
  return __builtin_bit_cast(unsigned short, (_Float16)f);
}
__device__ __forceinline__ float h2f(unsigned short h){
  return (float)__builtin_bit_cast(_Float16, h);
}
__device__ __forceinline__ f32x4 mfma_bf16(u16x8 a, u16x8 b, f32x4 c){
  return __builtin_amdgcn_mfma_f32_16x16x32_bf16(
      __builtin_bit_cast(bf16x8, a), __builtin_bit_cast(bf16x8, b), c, 0, 0, 0);
}
__device__ __forceinline__ float fast_sigmoid(float x){
  return __builtin_amdgcn_rcpf(1.0f + __builtin_amdgcn_exp2f(-1.44269504f * x));
}

constexpr int C_  = 256;
constexpr int L_  = 64;
constexpr int CHW = C_ * 64;   // 16384

// LDS operand layout (bf16/fp16, 256 c x 16 p): el(c,p) = ((c>>3)*16 + p)*8 + (c&7)
// B-fragment (kc, lane): b128 at kc*512 + (lane>>4)*128 + (lane&15)*8
// staging: b128 at (ss*16+sp)*8 ; epilogue rows ro..ro+3: b64 at
// ((ro>>3)*16 + m)*8 + (ro&7)

// Raw barrier: LDS ops drained, global prefetch loads stay in flight
#define BAR_LDS() do {                                        \
    asm volatile("s_waitcnt lgkmcnt(0)" ::: "memory");        \
    __builtin_amdgcn_s_barrier();                             \
    asm volatile("" ::: "memory");                            \
  } while (0)

// Phase-skewed schedule, constant per-role work (vs R3):
//   P: sf reads FIRST -> MFMA -> blend/write s_l -> staging commit+issue (tail)
//   G: staging commit+issue (head) -> zf reads -> MFMA -> sigmoid -> k write
// The P/G pair on each SIMD is thus offset by ~the staging-phase length, so
// LDS-read, MFMA, and VALU bursts of the two waves interleave instead of
// colliding (convoy-breaking).

__global__ __launch_bounds__(512, 2)
void kalman_kernel(const float* __restrict__ z,  const float* __restrict__ Wg,
                   const float* __restrict__ bg, const float* __restrict__ Wp,
                   const float* __restrict__ bp, float* __restrict__ out)
{
  __shared__ unsigned short zbuf[4][4096];   // z ring (2-step prefetch depth)
  __shared__ unsigned short sbuf[2][4096];   // state ping-pong (bf16)
  __shared__ unsigned short kbuf[2][4096];   // gain k ping-pong (fp16)

  // XCD swizzle: siblings (same b, q=0..3) share an XCD's L2
  const int lx  = (int)blockIdx.x;
  const int xcd = lx & 7;
  const int loc = lx >> 3;
  const int b   = xcd + 8 * (loc >> 2);
  const int q   = loc & 3;

  const int t    = (int)threadIdx.x;
  const int lane = t & 63;
  const int wv   = t >> 6;
  const int role = wv >> 2;           // 0 = P (predict+blend), 1 = G (gain, 1 step ahead)
  const int rw   = wv & 3;            // owns M-tiles rw*4 .. rw*4+3
  const int m    = lane & 15;
  const int g    = lane >> 4;

  const float* zg = z + (size_t)b * L_ * CHW + q * 16;

  // ---- weights for THIS role only: 4 M-tiles x 8 K-chunks (scalar RNE cvt) ----
  const float* Wsel = (role == 0) ? Wp : Wg;
  const float* bsrc = (role == 0) ? bp : bg;
  u16x8 wf[4][8];
  f32x4 bsel[4];
  #pragma unroll
  for (int mi = 0; mi < 4; ++mi){
    const int mt = rw * 4 + mi;
    const float* src = Wsel + (size_t)(mt * 16 + m) * 256 + g * 8;
    #pragma unroll
    for (int kc = 0; kc < 8; ++kc){
      f32x4 a0 = *(const f32x4*)(src + kc * 32);
      f32x4 a1 = *(const f32x4*)(src + kc * 32 + 4);
      #pragma unroll
      for (int j = 0; j < 4; ++j){
        wf[mi][kc][j]     = f2bf(a0[j]);
        wf[mi][kc][j + 4] = f2bf(a1[j]);
      }
    }
    bsel[mi] = *(const f32x4*)(bsrc + mt * 16 + g * 4);
  }

  // staging ids: thread t stages rows ss*8..+7 at pixel sp
  const int sp = t & 15;
  const int ss = t >> 4;
  const float* st_src = zg + ss * 8 * 64 + sp;
  const int st_dst = (ss * 16 + sp) * 8;
  const int boff   = g * 128 + m * 8;

  // ---- prologue: z0 -> sbuf[0], z1 -> zbuf[1], z2 -> zbuf[2]; issue z3 ----
  {
    float v0[8], v1[8], v2[8];
    #pragma unroll
    for (int j = 0; j < 8; ++j) v0[j] = st_src[j * 64];
    #pragma unroll
    for (int j = 0; j < 8; ++j) v1[j] = st_src[CHW + j * 64];
    #pragma unroll
    for (int j = 0; j < 8; ++j) v2[j] = st_src[2 * CHW + j * 64];
    u16x8 u0, u1, u2;
    #pragma unroll
    for (int j = 0; j < 8; ++j){ u0[j] = f2bf(v0[j]); u1[j] = f2bf(v1[j]); u2[j] = f2bf(v2[j]); }
    *(u16x8*)(&sbuf[0][st_dst]) = u0;
    *(u16x8*)(&zbuf[1][st_dst]) = u1;
    *(u16x8*)(&zbuf[2][st_dst]) = u2;
  }
  float pf[8];
  const float* pfp = st_src + 3 * (size_t)CHW;   // z3
  #pragma unroll
  for (int j = 0; j < 8; ++j) pf[j] = pfp[j * 64];
  pfp += CHW;                                    // next issue: z4
  __syncthreads();

  // k_1 from z_1 (G-waves only)
  if (role == 1){
    u16x8 zf[8];
    #pragma unroll
    for (int kc = 0; kc < 8; ++kc) zf[kc] = *(const u16x8*)(&zbuf[1][kc * 512 + boff]);
    f32x4 gl[4] = {bsel[0], bsel[1], bsel[2], bsel[3]};
    #pragma unroll
    for (int kc = 0; kc < 8; ++kc)
      #pragma unroll
      for (int mi = 0; mi < 4; ++mi)
        gl[mi] = mfma_bf16(wf[mi][kc], zf[kc], gl[mi]);
    #pragma unroll
    for (int mi = 0; mi < 4; ++mi){
      const int ro = (rw * 4 + mi) * 16 + g * 4;
      const int el = ((ro >> 3) * 16 + m) * 8 + (ro & 7);
      u16x4 kk;
      #pragma unroll
      for (int r = 0; r < 4; ++r) kk[r] = f2h(fast_sigmoid(gl[mi][r]));
      *(u16x4*)(&kbuf[1][el]) = kk;
    }
  }
  __syncthreads();

  for (int l = 1; l < 63; ++l){
    if (role == 0){
      // ================= P: critical chain first, staging at tail =================
      const unsigned short* sb  = sbuf[(l - 1) & 1];
      const unsigned short* zbl = zbuf[l & 3];
      const unsigned short* kb  = kbuf[l & 1];
      unsigned short* sbw = sbuf[l & 1];

      // sf reads FIRST (serial-chain head)
      u16x8 sf[8];
      #pragma unroll
      for (int kc = 0; kc < 8; ++kc) sf[kc] = *(const u16x8*)(sb + kc * 512 + boff);

      f32x4 zpA[4] = {bsel[0], bsel[1], bsel[2], bsel[3]};
      f32x4 zpB[4] = {{0,0,0,0},{0,0,0,0},{0,0,0,0},{0,0,0,0}};
      __builtin_amdgcn_s_setprio(1);
      #pragma unroll
      for (int kc = 0; kc < 4; ++kc)
        #pragma unroll
        for (int mi = 0; mi < 4; ++mi){
          zpA[mi] = mfma_bf16(wf[mi][kc],     sf[kc],     zpA[mi]);
          zpB[mi] = mfma_bf16(wf[mi][kc + 4], sf[kc + 4], zpB[mi]);
        }
      __builtin_amdgcn_s_setprio(0);

      u16x4 zi4[4], k4[4];
      #pragma unroll
      for (int mi = 0; mi < 4; ++mi){
        const int ro = (rw * 4 + mi) * 16 + g * 4;
        const int el = ((ro >> 3) * 16 + m) * 8 + (ro & 7);
        zi4[mi] = *(const u16x4*)(zbl + el);
        k4[mi]  = *(const u16x4*)(kb + el);
      }

      #pragma unroll
      for (int mi = 0; mi < 4; ++mi){
        const int ro = (rw * 4 + mi) * 16 + g * 4;
        const int el = ((ro >> 3) * 16 + m) * 8 + (ro & 7);
        u16x4 sh;
        #pragma unroll
        for (int r = 0; r < 4; ++r){
          float zpr = zpA[mi][r] + zpB[mi][r];
          float zh  = zpr + h2f(k4[mi][r]) * (bf2f(zi4[mi][r]) - zpr);
          sh[r] = f2bf(zh);
        }
        *(u16x4*)(sbw + el) = sh;
      }

      // staging at TAIL: commit z_{l+2}, issue z_{l+3}
      if (l <= 61){
        u16x8 u;
        #pragma unroll
        for (int j = 0; j < 8; ++j) u[j] = f2bf(pf[j]);
        *(u16x8*)(&zbuf[(l + 2) & 3][st_dst]) = u;
      }
      if (l <= 60){
        #pragma unroll
        for (int j = 0; j < 8; ++j) pf[j] = pfp[j * 64];
        pfp += CHW;
      }
    } else {
      // ================= G: staging at head, then gain for l+1 =================
      if (l <= 61){
        u16x8 u;
        #pragma unroll
        for (int j = 0; j < 8; ++j) u[j] = f2bf(pf[j]);
        *(u16x8*)(&zbuf[(l + 2) & 3][st_dst]) = u;
      }
      if (l <= 60){
        #pragma unroll
        for (int j = 0; j < 8; ++j) pf[j] = pfp[j * 64];
        pfp += CHW;
      }

      const unsigned short* zb = zbuf[(l + 1) & 3];
      unsigned short* kw = kbuf[(l + 1) & 1];

      u16x8 zf[8];
      #pragma unroll
      for (int kc = 0; kc < 8; ++kc) zf[kc] = *(const u16x8*)(zb + kc * 512 + boff);

      f32x4 gl[4] = {bsel[0], bsel[1], bsel[2], bsel[3]};
      #pragma unroll
      for (int kc = 0; kc < 8; ++kc)
        #pragma unroll
        for (int mi = 0; mi < 4; ++mi)
          gl[mi] = mfma_bf16(wf[mi][kc], zf[kc], gl[mi]);

      #pragma unroll
      for (int mi = 0; mi < 4; ++mi){
        const int ro = (rw * 4 + mi) * 16 + g * 4;
        const int el = ((ro >> 3) * 16 + m) * 8 + (ro & 7);
        u16x4 kk;
        #pragma unroll
        for (int r = 0; r < 4; ++r) kk[r] = f2h(fast_sigmoid(gl[mi][r]));
        *(u16x4*)(kw + el) = kk;
      }
    }

    BAR_LDS();
  }

  // ---- peeled final step l = 63 (P only): out (f32) from regs ----
  if (role == 0){
    const unsigned short* sb  = sbuf[0];          // s_62  ((63-1)&1)
    const unsigned short* zbl = zbuf[3];          // z_63  (63&3)
    const unsigned short* kb  = kbuf[1];          // k_63  (63&1)

    u16x8 sf[8];
    #pragma unroll
    for (int kc = 0; kc < 8; ++kc) sf[kc] = *(const u16x8*)(sb + kc * 512 + boff);
    u16x4 zi4[4], k4[4];
    #pragma unroll
    for (int mi = 0; mi < 4; ++mi){
      const int ro = (rw * 4 + mi) * 16 + g * 4;
      const int el = ((ro >> 3) * 16 + m) * 8 + (ro & 7);
      zi4[mi] = *(const u16x4*)(zbl + el);
      k4[mi]  = *(const u16x4*)(kb + el);
    }

    f32x4 zpA[4] = {bsel[0], bsel[1], bsel[2], bsel[3]};
    f32x4 zpB[4] = {{0,0,0,0},{0,0,0,0},{0,0,0,0},{0,0,0,0}};
    #pragma unroll
    for (int kc = 0; kc < 4; ++kc)
      #pragma unroll
      for (int mi = 0; mi < 4; ++mi){
        zpA[mi] = mfma_bf16(wf[mi][kc],     sf[kc],     zpA[mi]);
        zpB[mi] = mfma_bf16(wf[mi][kc + 4], sf[kc + 4], zpB[mi]);
      }

    #pragma unroll
    for (int mi = 0; mi < 4; ++mi){
      const int ro = (rw * 4 + mi) * 16 + g * 4;
      float* o = out + ((size_t)b * 256 + ro) * 64 + q * 16 + m;
      #pragma unroll
      for (int r = 0; r < 4; ++r){
        float zpr = zpA[mi][r] + zpB[mi][r];
        o[r * 64] = zpr + h2f(k4[mi][r]) * (bf2f(zi4[mi][r]) - zpr);
      }
    }
  }
}

extern "C" void kernel_launch(void* const* d_in, const int* in_sizes, int n_in,
                              void* d_out, int out_size, void* d_ws, size_t ws_size,
                              hipStream_t stream)
{
  const float* z  = (const float*)d_in[0];
  const float* Wg = (const float*)d_in[1];
  const float* bg = (const float*)d_in[2];
  const float* Wp = (const float*)d_in[3];
  const float* bp = (const float*)d_in[4];
  float* out = (float*)d_out;
  hipLaunchKernelGGL(kalman_kernel, dim3(256), dim3(512), 0, stream,
                     z, Wg, bg, Wp, bp, out);
}